// Round 7
// baseline (371.353 us; speedup 1.0000x reference)
//
#include <hip/hip_runtime.h>

typedef float f32x4 __attribute__((ext_vector_type(4)));
typedef short s16x8 __attribute__((ext_vector_type(8)));
typedef short s16x4 __attribute__((ext_vector_type(4)));
typedef int   i32x4 __attribute__((ext_vector_type(4)));

using abfrag = s16x8;  // 8 bf16 = 4 VGPRs

#define DI __device__ __forceinline__

DI unsigned short f2bf(float x) {  // RNE float->bf16
  unsigned u = __builtin_bit_cast(unsigned, x);
  u += 0x7fffu + ((u >> 16) & 1u);
  return (unsigned short)(u >> 16);
}
DI float bf2f(unsigned short h) {
  return __builtin_bit_cast(float, ((unsigned)h) << 16);
}

DI f32x4 MFMA(abfrag a, abfrag b, f32x4 c) {
  return __builtin_amdgcn_mfma_f32_16x16x32_bf16(a, b, c, 0, 0, 0);
}

// async global->LDS DMA, 16B/lane; LDS dest = wave-uniform base + lane*16
// (m104); per-lane source address carries the swizzle (m173).
DI void gld16(void* lds_base, const void* gsrc) {
  __builtin_amdgcn_global_load_lds(
      (const __attribute__((address_space(1))) unsigned int*)gsrc,
      (__attribute__((address_space(3))) unsigned int*)lds_base, 16, 0, 0);
}

#define MEMFENCE asm volatile("" ::: "memory")

// ---------------- fused fp32 -> bf16 conversion (4 sources, contiguous dst) --
__global__ void f2bf_multi(const float* __restrict__ s0, int n0,
                           const float* __restrict__ s1, int n1,
                           const float* __restrict__ s2, int n2,
                           const float* __restrict__ s3, int n3,
                           unsigned short* __restrict__ dst) {
  const int total = n0 + n1 + n2 + n3;  // vec4 units
  int i = blockIdx.x * blockDim.x + threadIdx.x;
  const int stride = gridDim.x * blockDim.x;
  for (; i < total; i += stride) {
    const float* s; int off;
    if (i < n0) { s = s0; off = i; }
    else if (i < n0 + n1) { s = s1; off = i - n0; }
    else if (i < n0 + n1 + n2) { s = s2; off = i - n0 - n1; }
    else { s = s3; off = i - n0 - n1 - n2; }
    f32x4 v = ((const f32x4*)s)[off];
    s16x4 o;
#pragma unroll
    for (int j = 0; j < 4; ++j) o[j] = (short)f2bf(v[j]);
    ((s16x4*)dst)[i] = o;
  }
}

// -------- fused gml layer (R7: 8-wave block, dbuf h+W, G from global) -------
// block = 512 thr = 8 waves (nl = w>>2, cv = w&3); tile = 2 n x 64 cols.
// Wave (nl,cv): rows 0..63 of n=2nn+nl, cols [pc0+16cv,+16), all 4 groups ->
// acc[4][4] = 64 VGPR. KT=32 (one MFMA k-step per kt, k-order identical to
// KT=64). LDS: lh[2][2][64][32] 16KB + lw[2][4][64][32] 32KB = 48KB ->
// 2 blocks/CU = 16 waves/CU (4/SIMD). ALL staging via gld16 (homogeneous
// vmcnt queue, 3 instrs/wave/kt), stage(kt+2) issued at iter kt -> one full
// kt of flight; vmcnt(3) drains exactly stage(kt+1). G never staged: read
// global->VGPR in the xo epilogue (L2-resident, each byte once).
// LDS slot-swizzle: [R][32] tiles, slot' = slot ^ (row&3) -> 2-way (free).
template <int C, bool RES>
__global__ __launch_bounds__(512, 4) void gml_layer_kernel(
    const unsigned short* __restrict__ hin,   // [128][64][C] bf16
    const unsigned short* __restrict__ Wb,    // [4][512][C] bf16
    const float* __restrict__ bias,           // [4][512]
    const unsigned short* __restrict__ Gb,    // [128][4][64][64] bf16
    unsigned short* __restrict__ hout) {      // [128][64][512] bf16
  constexpr int NT = C / 32;
  __shared__ short lh[2][2][64][32];   // [buf][nl][row][k] 16 KB
  __shared__ short lw[2][4][64][32];   // [buf][g][col][k] 32 KB

  const int tid  = threadIdx.x;
  const int w    = tid >> 6;
  const int lane = tid & 63;
  const int l15  = lane & 15;
  const int gq   = (lane >> 4) & 3;
  const int nl   = w >> 2;   // which of the 2 n's this wave computes
  const int cv   = w & 3;    // 16-col chunk within the 64-col tile
  const int nn   = blockIdx.x & 63;
  const int pc0  = (blockIdx.x >> 6) * 64;
  const int n    = 2 * nn + nl;
  // gld16 per-lane source swizzle for [R][32] tiles (dest = lane*16B linear):
  // dest row = r0 + (lane>>2), dest slot = lane&3; src slot = slot ^ (row&3).
  const int drow  = lane >> 2;                       // 0..15
  const int soff  = (((lane & 3) ^ (drow & 3)) << 3);  // src elem offset
  // ds_read fragment slot: window gq of row r, slot = gq ^ (r&3), r%4 = l15&3
  const int so = ((gq ^ (l15 & 3)) << 3);

  const unsigned short* hsrc = hin + (size_t)n * 64 * C;

  // wave w stages per kt: h 1 instr (nl' = w>>2, rows 16*(w&3)+..) and
  // W 2 instrs (g = w&3, rows 32*(w>>2)+..). 3 gld16 / wave / kt.
  const int hn   = w >> 2;        // nl this wave stages (== its own nl)
  const int hr0  = 16 * (w & 3);  // h row chunk
  const int wg   = w & 3;         // W group staged
  const int wr0  = 32 * (w >> 2); // W col chunk base
  const unsigned short* hstage = hin + ((size_t)(2 * nn + hn) * 64 + hr0 + drow) * C + soff;

  auto stage = [&](int buf, int kt) {  // 3 gld16, homogeneous queue
    gld16(&lh[buf][hn][hr0][0], hstage + kt * 32);
#pragma unroll
    for (int j = 0; j < 2; ++j)
      gld16(&lw[buf][wg][wr0 + 16 * j][0],
            Wb + (size_t)(wg * 512 + pc0 + wr0 + 16 * j + drow) * C + kt * 32 + soff);
  };

  f32x4 acc[4][4];  // [g][t] -- 64 VGPR
#pragma unroll
  for (int g = 0; g < 4; ++g)
#pragma unroll
    for (int t = 0; t < 4; ++t) acc[g][t] = f32x4{0.f, 0.f, 0.f, 0.f};

  // ---- prologue: stage(0), stage(1); drain stage(0) ----
  stage(0, 0);
  stage(1, 1);
  asm volatile("s_waitcnt vmcnt(3)" ::: "memory");
  MEMFENCE; __builtin_amdgcn_s_barrier(); MEMFENCE;

  for (int kt = 0; kt < NT; ++kt) {
    const int cur = kt & 1;
    // ---- compute: 4 A-reads + 4 B-reads -> 16 MFMA ----
    abfrag a[4];
#pragma unroll
    for (int t = 0; t < 4; ++t)
      a[t] = *(const abfrag*)&lh[cur][nl][16 * t + l15][so];
#pragma unroll
    for (int g = 0; g < 4; ++g) {
      const abfrag b = *(const abfrag*)&lw[cur][g][16 * cv + l15][so];
#pragma unroll
      for (int t = 0; t < 4; ++t) acc[g][t] = MFMA(a[t], b, acc[g][t]);
    }
    if (kt == NT - 1) break;  // epilogue touches no LDS
    MEMFENCE; __builtin_amdgcn_s_barrier(); MEMFENCE;  // readers of cur done

    if (kt + 2 < NT) {
      stage(cur, kt + 2);  // into just-retired buffers; flies one full kt
      asm volatile("s_waitcnt vmcnt(3)" ::: "memory");  // drains stage(kt+1)
    } else {
      asm volatile("s_waitcnt vmcnt(0)" ::: "memory");  // drain stage(NT-1)
    }
    MEMFENCE; __builtin_amdgcn_s_barrier(); MEMFENCE;
  }

  // ---- xo epilogue: G from global (L2), bias folded into bb ----
  float bv[4];
#pragma unroll
  for (int g = 0; g < 4; ++g) bv[g] = bias[g * 512 + pc0 + 16 * cv + l15];

  f32x4 xmax[4];
#pragma unroll
  for (int t = 0; t < 4; ++t) xmax[t] = f32x4{0.f, 0.f, 0.f, 0.f};

  const unsigned short* gbase = Gb + (size_t)n * 4 * 4096;
#pragma unroll
  for (int g = 0; g < 4; ++g) {
    // B-frags from acc[g]+bias; k-slot bijection (s, gq, slot i):
    // j = 16s + 4gq + (i&3) + 32*(i>>2)
    abfrag bb[2];
#pragma unroll
    for (int s = 0; s < 2; ++s) {
      abfrag t8;
#pragma unroll
      for (int r = 0; r < 4; ++r) {
        t8[r]     = (short)f2bf(acc[g][s][r] + bv[g]);
        t8[4 + r] = (short)f2bf(acc[g][s + 2][r] + bv[g]);
      }
      bb[s] = t8;
    }
    const unsigned short* gg = gbase + g * 4096;
#pragma unroll
    for (int t = 0; t < 4; ++t) {
      f32x4 xg = f32x4{0.f, 0.f, 0.f, 0.f};
#pragma unroll
      for (int s = 0; s < 2; ++s) {
        // A = G rows 16t+l15, elems 16s+4gq+{0..3} and +32 (from global)
        const unsigned short* gp = gg + (16 * t + l15) * 64 + 16 * s + 4 * gq;
        s16x4 alo = *(const s16x4*)gp;
        s16x4 ahi = *(const s16x4*)(gp + 32);
        abfrag a;
#pragma unroll
        for (int j = 0; j < 4; ++j) { a[j] = alo[j]; a[4 + j] = ahi[j]; }
        xg = MFMA(a, bb[s], xg);
      }
#pragma unroll
      for (int r = 0; r < 4; ++r)
        xmax[t][r] = fmaxf(xmax[t][r], xg[r]);  // init 0 => relu
    }
  }

  // ---- residual + store (C/D layout m89: col=lane&15, row=(lane>>4)*4+reg) --
  const int d = pc0 + 16 * cv + l15;
#pragma unroll
  for (int t = 0; t < 4; ++t)
#pragma unroll
    for (int r = 0; r < 4; ++r) {
      const int m = 16 * t + 4 * gq + r;
      float v = xmax[t][r];
      if constexpr (RES) v += bf2f(hin[(size_t)(n * 64 + m) * C + d]);
      hout[(size_t)(n * 64 + m) * 512 + d] = f2bf(v);
    }
}

// ---------------- final linear head (unchanged) ----------------
__global__ __launch_bounds__(256, 2) void final_kernel(
    const unsigned short* __restrict__ hin,  // [128][64][512] bf16
    const float* __restrict__ w1,            // [128][512]
    const float* __restrict__ b1,            // [128]
    const float* __restrict__ w2,            // [128]
    const float* __restrict__ b2,            // [1]
    float* __restrict__ out) {               // [128][64]
  constexpr int KT = 64, LW = 72, C = 512, NT = C / KT;
  __shared__ short sh_h[2][64][LW];
  __shared__ short sh_w[2][128][LW];
  __shared__ float red[4][64];
  const int tid = threadIdx.x;
  const int wv  = tid >> 6;
  const int l15 = tid & 15;
  const int gq  = (tid >> 4) & 3;
  const int n   = blockIdx.x;
  const int srow = tid >> 3;
  const int scol = (tid & 7) * 8;
  const unsigned short* hsrc = hin + (size_t)n * 64 * C;

  f32x4 acc[4][2];
#pragma unroll
  for (int t = 0; t < 4; ++t)
#pragma unroll
    for (int u = 0; u < 2; ++u) acc[t][u] = f32x4{0.f, 0.f, 0.f, 0.f};

  i32x4 hr[2], wr[4];
#pragma unroll
  for (int p = 0; p < 2; ++p)
    hr[p] = *(const i32x4*)(hsrc + (srow + p * 32) * C + scol);
#pragma unroll
  for (int p = 0; p < 4; ++p) {  // fp32 w1 -> bf16 in-stage
    const float* s = w1 + (srow + p * 32) * C + scol;
    f32x4 v0 = *(const f32x4*)s;
    f32x4 v1 = *(const f32x4*)(s + 4);
    s16x8 o;
#pragma unroll
    for (int j = 0; j < 4; ++j) { o[j] = (short)f2bf(v0[j]); o[4 + j] = (short)f2bf(v1[j]); }
    wr[p] = __builtin_bit_cast(i32x4, o);
  }
#pragma unroll
  for (int p = 0; p < 2; ++p) *(i32x4*)&sh_h[0][srow + p * 32][scol] = hr[p];
#pragma unroll
  for (int p = 0; p < 4; ++p) *(i32x4*)&sh_w[0][srow + p * 32][scol] = wr[p];

  for (int kt = 0; kt < NT; ++kt) {
    const int cur = kt & 1;
    if (kt + 1 < NT) {
#pragma unroll
      for (int p = 0; p < 2; ++p)
        hr[p] = *(const i32x4*)(hsrc + (srow + p * 32) * C + (kt + 1) * KT + scol);
#pragma unroll
      for (int p = 0; p < 4; ++p) {
        const float* s = w1 + (srow + p * 32) * C + (kt + 1) * KT + scol;
        f32x4 v0 = *(const f32x4*)s;
        f32x4 v1 = *(const f32x4*)(s + 4);
        s16x8 o;
#pragma unroll
        for (int j = 0; j < 4; ++j) { o[j] = (short)f2bf(v0[j]); o[4 + j] = (short)f2bf(v1[j]); }
        wr[p] = __builtin_bit_cast(i32x4, o);
      }
    }
    __syncthreads();
#pragma unroll
    for (int ks = 0; ks < 2; ++ks) {
      abfrag a[4], b[2];
#pragma unroll
      for (int t = 0; t < 4; ++t)
        a[t] = *(const abfrag*)&sh_h[cur][16 * t + l15][ks * 32 + gq * 8];
#pragma unroll
      for (int u = 0; u < 2; ++u)
        b[u] = *(const abfrag*)&sh_w[cur][32 * wv + 16 * u + l15][ks * 32 + gq * 8];
#pragma unroll
      for (int t = 0; t < 4; ++t)
#pragma unroll
        for (int u = 0; u < 2; ++u) acc[t][u] = MFMA(a[t], b[u], acc[t][u]);
    }
    if (kt + 1 < NT) {
#pragma unroll
      for (int p = 0; p < 2; ++p) *(i32x4*)&sh_h[1 - cur][srow + p * 32][scol] = hr[p];
#pragma unroll
      for (int p = 0; p < 4; ++p) *(i32x4*)&sh_w[1 - cur][srow + p * 32][scol] = wr[p];
    }
  }

  float b1v[2], w2v[2];
#pragma unroll
  for (int u = 0; u < 2; ++u) {
    b1v[u] = b1[32 * wv + 16 * u + l15];
    w2v[u] = w2[32 * wv + 16 * u + l15];
  }
  float part[4][4];
#pragma unroll
  for (int t = 0; t < 4; ++t)
#pragma unroll
    for (int r = 0; r < 4; ++r) {
      float s0 = 0.f;
#pragma unroll
      for (int u = 0; u < 2; ++u)
        s0 += fmaxf(acc[t][u][r] + b1v[u], 0.f) * w2v[u];
      part[t][r] = s0;
    }
#pragma unroll
  for (int t = 0; t < 4; ++t)
#pragma unroll
    for (int r = 0; r < 4; ++r)
#pragma unroll
      for (int msk = 1; msk < 16; msk <<= 1)
        part[t][r] += __shfl_xor(part[t][r], msk);
  if (l15 == 0) {
#pragma unroll
    for (int t = 0; t < 4; ++t)
#pragma unroll
      for (int r = 0; r < 4; ++r) red[wv][16 * t + 4 * gq + r] = part[t][r];
  }
  __syncthreads();
  if (tid < 64)
    out[(size_t)n * 64 + tid] =
        red[0][tid] + red[1][tid] + red[2][tid] + red[3][tid] + b2[0];
}

// ---------------- host ----------------
extern "C" void kernel_launch(void* const* d_in, const int* in_sizes, int n_in,
                              void* d_out, int out_size, void* d_ws, size_t ws_size,
                              hipStream_t stream) {
  const float* G   = (const float*)d_in[0];
  const float* x   = (const float*)d_in[1];
  const float* W0  = (const float*)d_in[2];
  const float* b0  = (const float*)d_in[3];
  const float* W   = (const float*)d_in[4];
  const float* b   = (const float*)d_in[5];
  const float* l1w = (const float*)d_in[6];
  const float* l1b = (const float*)d_in[7];
  const float* l2w = (const float*)d_in[8];
  const float* l2b = (const float*)d_in[9];
  float* out = (float*)d_out;

  char* p = (char*)d_ws;
  unsigned short* W0b = (unsigned short*)p; p += (size_t)4 * 512 * 128 * 2;
  unsigned short* Wb  = (unsigned short*)p; p += (size_t)7 * 4 * 512 * 512 * 2;
  unsigned short* Gb  = (unsigned short*)p; p += (size_t)128 * 4 * 64 * 64 * 2;
  unsigned short* xb  = (unsigned short*)p; p += (size_t)128 * 64 * 128 * 2;
  unsigned short* hA  = (unsigned short*)p; p += (size_t)128 * 64 * 512 * 2;
  unsigned short* hB  = (unsigned short*)p; p += (size_t)128 * 64 * 512 * 2;
  // total ws use: 38,273,024 bytes

  // one fused conversion: dsts (W0b,Wb,Gb,xb) are contiguous
  const int n0 = 4 * 512 * 128 / 4;
  const int n1 = 7 * 4 * 512 * 512 / 4;
  const int n2 = 128 * 4 * 64 * 64 / 4;
  const int n3 = 128 * 64 * 128 / 4;
  f2bf_multi<<<2048, 256, 0, stream>>>(W0, n0, W, n1, G, n2, x, n3, W0b);

  gml_layer_kernel<128, false><<<512, 512, 0, stream>>>(xb, W0b, b0, Gb, hA);
  const unsigned short* src = hA;
  unsigned short* dst = hB;
  for (int i = 0; i < 7; ++i) {
    gml_layer_kernel<512, true><<<512, 512, 0, stream>>>(
        src, Wb + (size_t)i * 4 * 512 * 512, b + (size_t)i * 4 * 512, Gb, dst);
    const unsigned short* t = src; src = dst; dst = (unsigned short*)t;
  }
  final_kernel<<<128, 256, 0, stream>>>(src, l1w, l1b, l2w, l2b, out);
}

// Round 8
// 211.312 us; speedup vs baseline: 1.7574x; 1.7574x over previous
//
#include <hip/hip_runtime.h>

typedef float f32x4 __attribute__((ext_vector_type(4)));
typedef short s16x8 __attribute__((ext_vector_type(8)));
typedef short s16x4 __attribute__((ext_vector_type(4)));
typedef int   i32x4 __attribute__((ext_vector_type(4)));

using abfrag = s16x8;  // 8 bf16 = 4 VGPRs

#define DI __device__ __forceinline__

DI unsigned short f2bf(float x) {  // RNE float->bf16
  unsigned u = __builtin_bit_cast(unsigned, x);
  u += 0x7fffu + ((u >> 16) & 1u);
  return (unsigned short)(u >> 16);
}
DI float bf2f(unsigned short h) {
  return __builtin_bit_cast(float, ((unsigned)h) << 16);
}

DI f32x4 MFMA(abfrag a, abfrag b, f32x4 c) {
  return __builtin_amdgcn_mfma_f32_16x16x32_bf16(a, b, c, 0, 0, 0);
}

// async global->LDS DMA, 16B/lane; LDS dest = wave-uniform base + lane*16
// (m104); per-lane source address carries the swizzle (m173).
DI void gld16(void* lds_base, const void* gsrc) {
  __builtin_amdgcn_global_load_lds(
      (const __attribute__((address_space(1))) unsigned int*)gsrc,
      (__attribute__((address_space(3))) unsigned int*)lds_base, 16, 0, 0);
}

// ---------------- fused fp32 -> bf16 conversion (4 sources, contiguous dst) --
__global__ void f2bf_multi(const float* __restrict__ s0, int n0,
                           const float* __restrict__ s1, int n1,
                           const float* __restrict__ s2, int n2,
                           const float* __restrict__ s3, int n3,
                           unsigned short* __restrict__ dst) {
  const int total = n0 + n1 + n2 + n3;  // vec4 units
  int i = blockIdx.x * blockDim.x + threadIdx.x;
  const int stride = gridDim.x * blockDim.x;
  for (; i < total; i += stride) {
    const float* s; int off;
    if (i < n0) { s = s0; off = i; }
    else if (i < n0 + n1) { s = s1; off = i - n0; }
    else if (i < n0 + n1 + n2) { s = s2; off = i - n0 - n1; }
    else { s = s3; off = i - n0 - n1 - n2; }
    f32x4 v = ((const f32x4*)s)[off];
    s16x4 o;
#pragma unroll
    for (int j = 0; j < 4; ++j) o[j] = (short)f2bf(v[j]);
    ((s16x4*)dst)[i] = o;
  }
}

// -------- fused gml layer (R8: R2 structure at 4 blocks/CU, 64-col tile) ----
// block = 256 thr = 4 waves; block computes (n, 64-col chunk pc0). Wave w owns
// cols [pc0+16w,+16), all 64 rows, all 4 groups: acc[4g][4t] = 64 VGPR.
// Per kt (KT=64): stage h (2 gld16/wave) + W g=w (8 gld16/wave) -> vmcnt(0)
// -> barrier -> compute (2ks x {4 A-reads, 4 B-reads, 16 MFMA}) -> barrier.
// Proven-race-free R2 sync; overlap comes from 4 independent blocks/CU
// (LDS = 8KB lh + 32KB lw = 40KB exactly -> 4 blocks/CU, 16 waves/CU).
// G overlaid on lw after the K-loop. Bias folded into epilogue (R6-verified).
// LDS rows are [64] wide with 8-slot XOR swizzle (slot ^= row&7): bank-clean.
template <int C, bool RES>
__global__ __launch_bounds__(256, 4) void gml_layer_kernel(
    const unsigned short* __restrict__ hin,   // [128][64][C] bf16
    const unsigned short* __restrict__ Wb,    // [4][512][C] bf16
    const float* __restrict__ bias,           // [4][512]
    const unsigned short* __restrict__ Gb,    // [128][4][64][64] bf16
    unsigned short* __restrict__ hout) {      // [128][64][512] bf16
  constexpr int NT = C / 64;
  __shared__ short lh[64][64];      // h tile, 8 KB
  __shared__ short lw[4][64][64];   // W tiles (g,col,k), 32 KB; G overlays

  const int tid  = threadIdx.x;
  const int w    = tid >> 6;       // wave = 16-col chunk
  const int lane = tid & 63;
  const int l15  = lane & 15;
  const int l7   = l15 & 7;
  const int gq   = (lane >> 4) & 3;
  const int n    = blockIdx.x & 127;
  const int pc0  = (blockIdx.x >> 7) * 64;
  const int lrow = lane >> 3;            // 0..7
  const int s8   = lane & 7;             // dest slot
  const int lsoff = ((s8 ^ lrow) << 3);  // swizzled src element offset

  const unsigned short* hsrc = hin + (size_t)n * 64 * C;

  f32x4 acc[4][4];  // [g][t]
#pragma unroll
  for (int g = 0; g < 4; ++g)
#pragma unroll
    for (int t = 0; t < 4; ++t) acc[g][t] = f32x4{0.f, 0.f, 0.f, 0.f};

  for (int kt = 0; kt < NT; ++kt) {
    // ---- stage h rows [16w,+16) (2) + W g=w all 64 cols (8) ----
#pragma unroll
    for (int j = 0; j < 2; ++j)
      gld16(&lh[16 * w + 8 * j][0],
            hsrc + (size_t)(16 * w + 8 * j + lrow) * C + kt * 64 + lsoff);
#pragma unroll
    for (int j = 0; j < 8; ++j)
      gld16(&lw[w][8 * j][0],
            Wb + (size_t)(w * 512 + pc0 + 8 * j + lrow) * C + kt * 64 + lsoff);
    asm volatile("s_waitcnt vmcnt(0)" ::: "memory");
    __syncthreads();

    // ---- compute: A-frags read once, reused across 4 groups ----
#pragma unroll
    for (int ks = 0; ks < 2; ++ks) {
      const int so = ((4 * ks + gq) ^ l7) << 3;
      abfrag a[4];
#pragma unroll
      for (int t = 0; t < 4; ++t)
        a[t] = *(const abfrag*)&lh[16 * t + l15][so];
#pragma unroll
      for (int g = 0; g < 4; ++g) {
        const abfrag b = *(const abfrag*)&lw[g][16 * w + l15][so];
#pragma unroll
        for (int t = 0; t < 4; ++t) acc[g][t] = MFMA(a[t], b, acc[g][t]);
      }
    }
    __syncthreads();  // readers done -> next kt (or G) may overwrite
  }

  // ---- stage G[n][g=w][64][64] into lw overlay ----
#pragma unroll
  for (int j = 0; j < 8; ++j)
    gld16(&lw[w][8 * j][0],
          Gb + (size_t)(n * 4 + w) * 4096 + (8 * j + lrow) * 64 + lsoff);
  asm volatile("s_waitcnt vmcnt(0)" ::: "memory");
  __syncthreads();

  // ---- xo = G * (multi+bias) per group; relu+max fused ----
  float bv[4];
#pragma unroll
  for (int g = 0; g < 4; ++g) bv[g] = bias[g * 512 + pc0 + 16 * w + l15];

  f32x4 xmax[4];
#pragma unroll
  for (int t = 0; t < 4; ++t) xmax[t] = f32x4{0.f, 0.f, 0.f, 0.f};

#pragma unroll
  for (int g = 0; g < 4; ++g) {
    // B-frags from acc[g]+bias; k-slot bijection (s, gq, slot i):
    // j = 16s + 4gq + (i&3) + 32*(i>>2)
    abfrag bb[2];
#pragma unroll
    for (int s = 0; s < 2; ++s) {
      abfrag t8;
#pragma unroll
      for (int r = 0; r < 4; ++r) {
        t8[r]     = (short)f2bf(acc[g][s][r] + bv[g]);
        t8[4 + r] = (short)f2bf(acc[g][s + 2][r] + bv[g]);
      }
      bb[s] = t8;
    }
#pragma unroll
    for (int t = 0; t < 4; ++t) {
      const short* grow = &lw[g][16 * t + l15][0];
      f32x4 xg = f32x4{0.f, 0.f, 0.f, 0.f};
#pragma unroll
      for (int s = 0; s < 2; ++s) {
        // A = G rows 16t+l15, elems 16s+4gq+{0..3} and +32 (swizzled slots)
        const int slot = 2 * s + (gq >> 1);
        const int e1 = ((slot ^ l7) << 3) + ((gq & 1) << 2);
        const int e2 = (((slot + 4) ^ l7) << 3) + ((gq & 1) << 2);
        s16x4 alo = *(const s16x4*)(grow + e1);
        s16x4 ahi = *(const s16x4*)(grow + e2);
        abfrag a;
#pragma unroll
        for (int j = 0; j < 4; ++j) { a[j] = alo[j]; a[4 + j] = ahi[j]; }
        xg = MFMA(a, bb[s], xg);
      }
#pragma unroll
      for (int r = 0; r < 4; ++r)
        xmax[t][r] = fmaxf(xmax[t][r], xg[r]);  // init 0 => relu
    }
  }

  // ---- residual + store (C/D layout m89: col=lane&15, row=(lane>>4)*4+reg) --
  const int d = pc0 + 16 * w + l15;
#pragma unroll
  for (int t = 0; t < 4; ++t)
#pragma unroll
    for (int r = 0; r < 4; ++r) {
      const int m = 16 * t + 4 * gq + r;
      float v = xmax[t][r];
      if constexpr (RES) v += bf2f(hin[(size_t)(n * 64 + m) * C + d]);
      hout[(size_t)(n * 64 + m) * 512 + d] = f2bf(v);
    }
}

// ---------------- final linear head (unchanged) ----------------
__global__ __launch_bounds__(256, 2) void final_kernel(
    const unsigned short* __restrict__ hin,  // [128][64][512] bf16
    const float* __restrict__ w1,            // [128][512]
    const float* __restrict__ b1,            // [128]
    const float* __restrict__ w2,            // [128]
    const float* __restrict__ b2,            // [1]
    float* __restrict__ out) {               // [128][64]
  constexpr int KT = 64, LW = 72, C = 512, NT = C / KT;
  __shared__ short sh_h[2][64][LW];
  __shared__ short sh_w[2][128][LW];
  __shared__ float red[4][64];
  const int tid = threadIdx.x;
  const int wv  = tid >> 6;
  const int l15 = tid & 15;
  const int gq  = (tid >> 4) & 3;
  const int n   = blockIdx.x;
  const int srow = tid >> 3;
  const int scol = (tid & 7) * 8;
  const unsigned short* hsrc = hin + (size_t)n * 64 * C;

  f32x4 acc[4][2];
#pragma unroll
  for (int t = 0; t < 4; ++t)
#pragma unroll
    for (int u = 0; u < 2; ++u) acc[t][u] = f32x4{0.f, 0.f, 0.f, 0.f};

  i32x4 hr[2], wr[4];
#pragma unroll
  for (int p = 0; p < 2; ++p)
    hr[p] = *(const i32x4*)(hsrc + (srow + p * 32) * C + scol);
#pragma unroll
  for (int p = 0; p < 4; ++p) {  // fp32 w1 -> bf16 in-stage
    const float* s = w1 + (srow + p * 32) * C + scol;
    f32x4 v0 = *(const f32x4*)s;
    f32x4 v1 = *(const f32x4*)(s + 4);
    s16x8 o;
#pragma unroll
    for (int j = 0; j < 4; ++j) { o[j] = (short)f2bf(v0[j]); o[4 + j] = (short)f2bf(v1[j]); }
    wr[p] = __builtin_bit_cast(i32x4, o);
  }
#pragma unroll
  for (int p = 0; p < 2; ++p) *(i32x4*)&sh_h[0][srow + p * 32][scol] = hr[p];
#pragma unroll
  for (int p = 0; p < 4; ++p) *(i32x4*)&sh_w[0][srow + p * 32][scol] = wr[p];

  for (int kt = 0; kt < NT; ++kt) {
    const int cur = kt & 1;
    if (kt + 1 < NT) {
#pragma unroll
      for (int p = 0; p < 2; ++p)
        hr[p] = *(const i32x4*)(hsrc + (srow + p * 32) * C + (kt + 1) * KT + scol);
#pragma unroll
      for (int p = 0; p < 4; ++p) {
        const float* s = w1 + (srow + p * 32) * C + (kt + 1) * KT + scol;
        f32x4 v0 = *(const f32x4*)s;
        f32x4 v1 = *(const f32x4*)(s + 4);
        s16x8 o;
#pragma unroll
        for (int j = 0; j < 4; ++j) { o[j] = (short)f2bf(v0[j]); o[4 + j] = (short)f2bf(v1[j]); }
        wr[p] = __builtin_bit_cast(i32x4, o);
      }
    }
    __syncthreads();
#pragma unroll
    for (int ks = 0; ks < 2; ++ks) {
      abfrag a[4], b[2];
#pragma unroll
      for (int t = 0; t < 4; ++t)
        a[t] = *(const abfrag*)&sh_h[cur][16 * t + l15][ks * 32 + gq * 8];
#pragma unroll
      for (int u = 0; u < 2; ++u)
        b[u] = *(const abfrag*)&sh_w[cur][32 * wv + 16 * u + l15][ks * 32 + gq * 8];
#pragma unroll
      for (int t = 0; t < 4; ++t)
#pragma unroll
        for (int u = 0; u < 2; ++u) acc[t][u] = MFMA(a[t], b[u], acc[t][u]);
    }
    if (kt + 1 < NT) {
#pragma unroll
      for (int p = 0; p < 2; ++p) *(i32x4*)&sh_h[1 - cur][srow + p * 32][scol] = hr[p];
#pragma unroll
      for (int p = 0; p < 4; ++p) *(i32x4*)&sh_w[1 - cur][srow + p * 32][scol] = wr[p];
    }
  }

  float b1v[2], w2v[2];
#pragma unroll
  for (int u = 0; u < 2; ++u) {
    b1v[u] = b1[32 * wv + 16 * u + l15];
    w2v[u] = w2[32 * wv + 16 * u + l15];
  }
  float part[4][4];
#pragma unroll
  for (int t = 0; t < 4; ++t)
#pragma unroll
    for (int r = 0; r < 4; ++r) {
      float s0 = 0.f;
#pragma unroll
      for (int u = 0; u < 2; ++u)
        s0 += fmaxf(acc[t][u][r] + b1v[u], 0.f) * w2v[u];
      part[t][r] = s0;
    }
#pragma unroll
  for (int t = 0; t < 4; ++t)
#pragma unroll
    for (int r = 0; r < 4; ++r)
#pragma unroll
      for (int msk = 1; msk < 16; msk <<= 1)
        part[t][r] += __shfl_xor(part[t][r], msk);
  if (l15 == 0) {
#pragma unroll
    for (int t = 0; t < 4; ++t)
#pragma unroll
      for (int r = 0; r < 4; ++r) red[wv][16 * t + 4 * gq + r] = part[t][r];
  }
  __syncthreads();
  if (tid < 64)
    out[(size_t)n * 64 + tid] =
        red[0][tid] + red[1][tid] + red[2][tid] + red[3][tid] + b2[0];
}

// ---------------- host ----------------
extern "C" void kernel_launch(void* const* d_in, const int* in_sizes, int n_in,
                              void* d_out, int out_size, void* d_ws, size_t ws_size,
                              hipStream_t stream) {
  const float* G   = (const float*)d_in[0];
  const float* x   = (const float*)d_in[1];
  const float* W0  = (const float*)d_in[2];
  const float* b0  = (const float*)d_in[3];
  const float* W   = (const float*)d_in[4];
  const float* b   = (const float*)d_in[5];
  const float* l1w = (const float*)d_in[6];
  const float* l1b = (const float*)d_in[7];
  const float* l2w = (const float*)d_in[8];
  const float* l2b = (const float*)d_in[9];
  float* out = (float*)d_out;

  char* p = (char*)d_ws;
  unsigned short* W0b = (unsigned short*)p; p += (size_t)4 * 512 * 128 * 2;
  unsigned short* Wb  = (unsigned short*)p; p += (size_t)7 * 4 * 512 * 512 * 2;
  unsigned short* Gb  = (unsigned short*)p; p += (size_t)128 * 4 * 64 * 64 * 2;
  unsigned short* xb  = (unsigned short*)p; p += (size_t)128 * 64 * 128 * 2;
  unsigned short* hA  = (unsigned short*)p; p += (size_t)128 * 64 * 512 * 2;
  unsigned short* hB  = (unsigned short*)p; p += (size_t)128 * 64 * 512 * 2;
  // total ws use: 38,273,024 bytes

  // one fused conversion: dsts (W0b,Wb,Gb,xb) are contiguous
  const int n0 = 4 * 512 * 128 / 4;
  const int n1 = 7 * 4 * 512 * 512 / 4;
  const int n2 = 128 * 4 * 64 * 64 / 4;
  const int n3 = 128 * 64 * 128 / 4;
  f2bf_multi<<<4096, 256, 0, stream>>>(W0, n0, W, n1, G, n2, x, n3, W0b);

  gml_layer_kernel<128, false><<<1024, 256, 0, stream>>>(xb, W0b, b0, Gb, hA);
  const unsigned short* src = hA;
  unsigned short* dst = hB;
  for (int i = 0; i < 7; ++i) {
    gml_layer_kernel<512, true><<<1024, 256, 0, stream>>>(
        src, Wb + (size_t)i * 4 * 512 * 512, b + (size_t)i * 4 * 512, Gb, dst);
    const unsigned short* t = src; src = dst; dst = (unsigned short*)t;
  }
  final_kernel<<<128, 256, 0, stream>>>(src, l1w, l1b, l2w, l2b, out);
}